// Round 1
// baseline (1365.385 us; speedup 1.0000x reference)
//
#include <hip/hip_runtime.h>
#include <math.h>

#define NNODES 50000
#define NEDGES 800000

// ---- order-preserving float<->uint transform for atomicMax on floats ----
__device__ __forceinline__ unsigned f2ord(float f) {
    unsigned b = __float_as_uint(f);
    return (b & 0x80000000u) ? ~b : (b | 0x80000000u);
}
__device__ __forceinline__ float ord2f(unsigned u) {
    unsigned b = (u & 0x80000000u) ? (u & 0x7FFFFFFFu) : ~u;
    return __uint_as_float(b);
}

// ---- generic fp32 GEMM: C[M,Nc] = A[M,K] @ B[K,Nc], 64x64 tile, 4x4/thread ----
__global__ void gemm_f32(const float* __restrict__ A, const float* __restrict__ B,
                         float* __restrict__ C, int M, int K, int Nc) {
    __shared__ float As[64][17];
    __shared__ float Bs[16][65];
    int tid = threadIdx.x;
    int tx = tid & 15, ty = tid >> 4;
    int m0 = blockIdx.y * 64, n0 = blockIdx.x * 64;
    float acc[4][4] = {};
    for (int k0 = 0; k0 < K; k0 += 16) {
#pragma unroll
        for (int i = 0; i < 4; i++) {
            int r = (tid >> 4) + i * 16, c = tid & 15;
            int gr = m0 + r, gc = k0 + c;
            As[r][c] = (gr < M && gc < K) ? A[(size_t)gr * K + gc] : 0.f;
        }
#pragma unroll
        for (int i = 0; i < 4; i++) {
            int kk = (tid >> 6) + i * 4, c = tid & 63;
            int gk = k0 + kk, gc = n0 + c;
            Bs[kk][c] = (gk < K && gc < Nc) ? B[(size_t)gk * Nc + gc] : 0.f;
        }
        __syncthreads();
#pragma unroll
        for (int kk = 0; kk < 16; kk++) {
            float a[4], b[4];
#pragma unroll
            for (int i = 0; i < 4; i++) a[i] = As[ty * 4 + i][kk];
#pragma unroll
            for (int j = 0; j < 4; j++) b[j] = Bs[kk][tx * 4 + j];
#pragma unroll
            for (int i = 0; i < 4; i++)
#pragma unroll
                for (int j = 0; j < 4; j++) acc[i][j] += a[i] * b[j];
        }
        __syncthreads();
    }
#pragma unroll
    for (int i = 0; i < 4; i++) {
        int gr = m0 + ty * 4 + i;
        if (gr >= M) continue;
#pragma unroll
        for (int j = 0; j < 4; j++) {
            int gc = n0 + tx * 4 + j;
            if (gc < Nc) C[(size_t)gr * Nc + gc] = acc[i][j];
        }
    }
}

// ---- per-node attention scalars: as[n,h]=dot(h[n,h,:],a_src[h,:]) etc. ----
// one 64-lane wave per node, 4 waves per block
template <int H>
__global__ void asad_kernel(const float* __restrict__ hbuf, const float* __restrict__ a_src,
                            const float* __restrict__ a_dst, float* __restrict__ as_,
                            float* __restrict__ ad_, int n) {
    int node = blockIdx.x * 4 + (threadIdx.x >> 6);
    int lane = threadIdx.x & 63;
    if (node >= n) return;
#pragma unroll
    for (int hh = 0; hh < H; hh++) {
        float v = hbuf[(size_t)node * (H * 64) + hh * 64 + lane];
        float vs = v * a_src[hh * 64 + lane];
        float vd = v * a_dst[hh * 64 + lane];
#pragma unroll
        for (int off = 32; off > 0; off >>= 1) {
            vs += __shfl_down(vs, off);
            vd += __shfl_down(vd, off);
        }
        if (lane == 0) {
            as_[node * H + hh] = vs;
            ad_[node * H + hh] = vd;
        }
    }
}

// ---- edge pass 1: segment max of leaky_relu(as[src]+ad[dst]) over dst ----
template <int H>
__global__ void edge_max_kernel(const int* __restrict__ ei, const float* __restrict__ as_,
                                const float* __restrict__ ad_, unsigned* __restrict__ m,
                                int nE, int nT) {
    long long idx = (long long)blockIdx.x * blockDim.x + threadIdx.x;
    if (idx >= (long long)nT * H) return;
    int e = (int)(idx / H), hh = (int)(idx % H);
    int src, dst;
    if (e < nE) { src = ei[e]; dst = ei[nE + e]; } else { src = dst = e - nE; }
    float ev = as_[src * H + hh] + ad_[dst * H + hh];
    ev = ev > 0.f ? ev : 0.2f * ev;
    atomicMax(&m[dst * H + hh], f2ord(ev));
}

// ---- edge pass 2: segment sum of exp(e - m[dst]) ----
template <int H>
__global__ void edge_sum_kernel(const int* __restrict__ ei, const float* __restrict__ as_,
                                const float* __restrict__ ad_, const unsigned* __restrict__ m,
                                float* __restrict__ s, int nE, int nT) {
    long long idx = (long long)blockIdx.x * blockDim.x + threadIdx.x;
    if (idx >= (long long)nT * H) return;
    int e = (int)(idx / H), hh = (int)(idx % H);
    int src, dst;
    if (e < nE) { src = ei[e]; dst = ei[nE + e]; } else { src = dst = e - nE; }
    float ev = as_[src * H + hh] + ad_[dst * H + hh];
    ev = ev > 0.f ? ev : 0.2f * ev;
    float ex = expf(ev - ord2f(m[dst * H + hh]));
    atomicAdd(&s[dst * H + hh], ex);
}

// ---- edge pass 3: out[dst,h,:] += alpha * h[src,h,:], one wave per edge ----
template <int H>
__global__ void edge_agg_kernel(const int* __restrict__ ei, const float* __restrict__ as_,
                                const float* __restrict__ ad_, const unsigned* __restrict__ m,
                                const float* __restrict__ s, const float* __restrict__ hbuf,
                                float* __restrict__ out, int nE, int nT) {
    int e = blockIdx.x * 4 + (threadIdx.x >> 6);
    int lane = threadIdx.x & 63;
    if (e >= nT) return;
    int src, dst;
    if (e < nE) { src = ei[e]; dst = ei[nE + e]; } else { src = dst = e - nE; }
#pragma unroll
    for (int hh = 0; hh < H; hh++) {
        float ev = as_[src * H + hh] + ad_[dst * H + hh];
        ev = ev > 0.f ? ev : 0.2f * ev;
        float alpha = expf(ev - ord2f(m[dst * H + hh])) / (s[dst * H + hh] + 1e-16f);
        float v = hbuf[(size_t)src * (H * 64) + hh * 64 + lane];
        atomicAdd(&out[(size_t)dst * (H * 64) + hh * 64 + lane], alpha * v);
    }
}

// ---- elementwise bias + ELU (in-place) ----
__global__ void bias_elu_kernel(float* __restrict__ buf, const float* __restrict__ b,
                                int total, int mask) {
    int idx = blockIdx.x * blockDim.x + threadIdx.x;
    if (idx >= total) return;
    float v = buf[idx] + b[idx & mask];
    buf[idx] = v > 0.f ? v : (expf(v) - 1.f);
}

// ---- fused classifier: out = relu(z@W3+b3)@W4+b4, 64 rows per block ----
__global__ void classifier_kernel(const float* __restrict__ z, const float* __restrict__ W3,
                                  const float* __restrict__ b3, const float* __restrict__ W4,
                                  const float* __restrict__ b4, float* __restrict__ out, int n) {
    __shared__ float zt[64][65];
    __shared__ float w3s[64 * 32];
    __shared__ float hid[64][33];
    __shared__ float w4s[64], b3s[32], b4s[2];
    int t = threadIdx.x;
    int r0 = blockIdx.x * 64;
#pragma unroll
    for (int i = 0; i < 16; i++) {
        int j = i * 256 + t;
        int row = j >> 6, col = j & 63;
        int gr = r0 + row;
        zt[row][col] = (gr < n) ? z[(size_t)gr * 64 + col] : 0.f;
    }
#pragma unroll
    for (int i = 0; i < 8; i++) w3s[i * 256 + t] = W3[i * 256 + t];
    if (t < 64) w4s[t] = W4[t];
    if (t < 32) b3s[t] = b3[t];
    if (t < 2) b4s[t] = b4[t];
    __syncthreads();
#pragma unroll
    for (int i = 0; i < 8; i++) {
        int row = (t >> 5) + i * 8;
        int col = t & 31;
        float acc = b3s[col];
#pragma unroll
        for (int k = 0; k < 64; k++) acc += zt[row][k] * w3s[k * 32 + col];
        hid[row][col] = acc > 0.f ? acc : 0.f;
    }
    __syncthreads();
    if (t < 128) {
        int row = t >> 1, c = t & 1;
        int gr = r0 + row;
        if (gr < n) {
            float acc = b4s[c];
#pragma unroll
            for (int k = 0; k < 32; k++) acc += hid[row][k] * w4s[k * 2 + c];
            out[(size_t)gr * 2 + c] = acc;
        }
    }
}

extern "C" void kernel_launch(void* const* d_in, const int* in_sizes, int n_in,
                              void* d_out, int out_size, void* d_ws, size_t ws_size,
                              hipStream_t stream) {
    const float* x      = (const float*)d_in[0];
    const int*   ei     = (const int*)d_in[1];
    const float* W1     = (const float*)d_in[2];
    const float* a_src1 = (const float*)d_in[3];
    const float* a_dst1 = (const float*)d_in[4];
    const float* b1     = (const float*)d_in[5];
    const float* W2     = (const float*)d_in[6];
    const float* a_src2 = (const float*)d_in[7];
    const float* a_dst2 = (const float*)d_in[8];
    const float* b2     = (const float*)d_in[9];
    const float* W3     = (const float*)d_in[10];
    const float* b3     = (const float*)d_in[11];
    const float* W4     = (const float*)d_in[12];
    const float* b4     = (const float*)d_in[13];
    float* out = (float*)d_out;

    const int N = NNODES, E = NEDGES, ET = E + N;

    float* ws = (float*)d_ws;
    float* h1   = ws;                                  // N*256
    float* out1 = ws + (size_t)N * 256;                // N*256 (becomes x2)
    float* as1  = ws + (size_t)2 * N * 256;            // N*4
    float* ad1  = as1 + (size_t)N * 4;                 // N*4
    unsigned* m1 = (unsigned*)(ad1 + (size_t)N * 4);   // N*4
    float* s1   = (float*)(m1 + (size_t)N * 4);        // N*4
    // layer-2 buffers reuse the h1 region (h1 dead after layer-1 aggregation)
    float* h2   = h1;                                  // N*64
    float* out2 = h1 + (size_t)N * 64;                 // N*64

    dim3 blk(256);

    // ---- Layer 1 (H=4, C=64) ----
    gemm_f32<<<dim3(4, (N + 63) / 64), blk, 0, stream>>>(x, W1, h1, N, 128, 256);
    asad_kernel<4><<<(N + 3) / 4, blk, 0, stream>>>(h1, a_src1, a_dst1, as1, ad1, N);
    hipMemsetAsync(out1, 0, (size_t)N * 256 * sizeof(float), stream);
    hipMemsetAsync(m1, 0, (size_t)N * 4 * sizeof(unsigned) * 2, stream);  // m1 + s1
    {
        long long tot = (long long)ET * 4;
        int nb = (int)((tot + 255) / 256);
        edge_max_kernel<4><<<nb, blk, 0, stream>>>(ei, as1, ad1, m1, E, ET);
        edge_sum_kernel<4><<<nb, blk, 0, stream>>>(ei, as1, ad1, m1, s1, E, ET);
    }
    edge_agg_kernel<4><<<(ET + 3) / 4, blk, 0, stream>>>(ei, as1, ad1, m1, s1, h1, out1, E, ET);
    bias_elu_kernel<<<((size_t)N * 256 + 255) / 256, blk, 0, stream>>>(out1, b1, N * 256, 255);

    // ---- Layer 2 (H=1, C=64) ----
    gemm_f32<<<dim3(1, (N + 63) / 64), blk, 0, stream>>>(out1, W2, h2, N, 256, 64);
    asad_kernel<1><<<(N + 3) / 4, blk, 0, stream>>>(h2, a_src2, a_dst2, as1, ad1, N);
    hipMemsetAsync(out2, 0, (size_t)N * 64 * sizeof(float), stream);
    hipMemsetAsync(m1, 0, (size_t)N * 4 * sizeof(unsigned) * 2, stream);
    {
        int nb = (ET + 255) / 256;
        edge_max_kernel<1><<<nb, blk, 0, stream>>>(ei, as1, ad1, m1, E, ET);
        edge_sum_kernel<1><<<nb, blk, 0, stream>>>(ei, as1, ad1, m1, s1, E, ET);
    }
    edge_agg_kernel<1><<<(ET + 3) / 4, blk, 0, stream>>>(ei, as1, ad1, m1, s1, h2, out2, E, ET);
    bias_elu_kernel<<<((size_t)N * 64 + 255) / 256, blk, 0, stream>>>(out2, b2, N * 64, 63);

    // ---- Classifier ----
    classifier_kernel<<<(N + 63) / 64, blk, 0, stream>>>(out2, W3, b3, W4, b4, out, N);
}

// Round 2
// 614.731 us; speedup vs baseline: 2.2211x; 2.2211x over previous
//
#include <hip/hip_runtime.h>
#include <math.h>

#define NNODES 50000
#define NEDGES 800000

// ============ fp32 GEMM: C[M,Nc] = A[M,K] @ B[K,Nc], 64x64 tile ============
__global__ void gemm_f32(const float* __restrict__ A, const float* __restrict__ B,
                         float* __restrict__ C, int M, int K, int Nc) {
    __shared__ float As[64][17];
    __shared__ float Bs[16][65];
    int tid = threadIdx.x;
    int tx = tid & 15, ty = tid >> 4;
    int m0 = blockIdx.y * 64, n0 = blockIdx.x * 64;
    float acc[4][4] = {};
    for (int k0 = 0; k0 < K; k0 += 16) {
#pragma unroll
        for (int i = 0; i < 4; i++) {
            int r = (tid >> 4) + i * 16, c = tid & 15;
            int gr = m0 + r, gc = k0 + c;
            As[r][c] = (gr < M && gc < K) ? A[(size_t)gr * K + gc] : 0.f;
        }
#pragma unroll
        for (int i = 0; i < 4; i++) {
            int kk = (tid >> 6) + i * 4, c = tid & 63;
            int gk = k0 + kk, gc = n0 + c;
            Bs[kk][c] = (gk < K && gc < Nc) ? B[(size_t)gk * Nc + gc] : 0.f;
        }
        __syncthreads();
#pragma unroll
        for (int kk = 0; kk < 16; kk++) {
            float a[4], b[4];
#pragma unroll
            for (int i = 0; i < 4; i++) a[i] = As[ty * 4 + i][kk];
#pragma unroll
            for (int j = 0; j < 4; j++) b[j] = Bs[kk][tx * 4 + j];
#pragma unroll
            for (int i = 0; i < 4; i++)
#pragma unroll
                for (int j = 0; j < 4; j++) acc[i][j] += a[i] * b[j];
        }
        __syncthreads();
    }
#pragma unroll
    for (int i = 0; i < 4; i++) {
        int gr = m0 + ty * 4 + i;
        if (gr >= M) continue;
#pragma unroll
        for (int j = 0; j < 4; j++) {
            int gc = n0 + tx * 4 + j;
            if (gc < Nc) C[(size_t)gr * Nc + gc] = acc[i][j];
        }
    }
}

// ============ per-node attention scalars ============
template <int H>
__global__ void asad_kernel(const float* __restrict__ hbuf, const float* __restrict__ a_src,
                            const float* __restrict__ a_dst, float* __restrict__ as_,
                            float* __restrict__ ad_, int n) {
    int node = blockIdx.x * 4 + (threadIdx.x >> 6);
    int lane = threadIdx.x & 63;
    if (node >= n) return;
#pragma unroll
    for (int hh = 0; hh < H; hh++) {
        float v = hbuf[(size_t)node * (H * 64) + hh * 64 + lane];
        float vs = v * a_src[hh * 64 + lane];
        float vd = v * a_dst[hh * 64 + lane];
#pragma unroll
        for (int off = 32; off > 0; off >>= 1) {
            vs += __shfl_down(vs, off);
            vd += __shfl_down(vd, off);
        }
        if (lane == 0) {
            as_[node * H + hh] = vs;
            ad_[node * H + hh] = vd;
        }
    }
}

// ============ CSR build: histogram -> scan -> scatter ============
__global__ void deg_hist(const int* __restrict__ ei, int* __restrict__ deg, int nE, int nT) {
    int idx = blockIdx.x * blockDim.x + threadIdx.x;
    if (idx >= nT) return;
    int dst = (idx < nE) ? ei[nE + idx] : idx - nE;
    atomicAdd(&deg[dst], 1);
}

// per-block exclusive scan of 256 elements; write per-block totals
__global__ void scan_block(const int* __restrict__ deg, int* __restrict__ rowptr,
                           int* __restrict__ blocksums, int n) {
    __shared__ int tmp[256];
    int tid = threadIdx.x;
    int gid = blockIdx.x * 256 + tid;
    int v = (gid < n) ? deg[gid] : 0;
    tmp[tid] = v;
    __syncthreads();
    for (int off = 1; off < 256; off <<= 1) {
        int t = (tid >= off) ? tmp[tid - off] : 0;
        __syncthreads();
        tmp[tid] += t;
        __syncthreads();
    }
    if (gid < n) rowptr[gid] = tmp[tid] - v;  // exclusive within block
    if (tid == 255) blocksums[blockIdx.x] = tmp[tid];
}

// single-block exclusive scan of block sums (nb <= 256)
__global__ void scan_sums(int* __restrict__ bs, int nb) {
    __shared__ int tmp[256];
    int tid = threadIdx.x;
    int v = (tid < nb) ? bs[tid] : 0;
    tmp[tid] = v;
    __syncthreads();
    for (int off = 1; off < 256; off <<= 1) {
        int t = (tid >= off) ? tmp[tid - off] : 0;
        __syncthreads();
        tmp[tid] += t;
        __syncthreads();
    }
    if (tid < nb) bs[tid] = tmp[tid] - v;
}

// add block offsets, finalize rowptr, init cursor
__global__ void scan_add(int* __restrict__ rowptr, const int* __restrict__ bs,
                         int* __restrict__ cursor, int n, int nT) {
    int gid = blockIdx.x * 256 + threadIdx.x;
    if (gid < n) {
        int r = rowptr[gid] + bs[blockIdx.x];
        rowptr[gid] = r;
        cursor[gid] = r;
    }
    if (gid == 0) rowptr[n] = nT;
}

__global__ void csr_scatter(const int* __restrict__ ei, int* __restrict__ cursor,
                            int* __restrict__ csr_src, int nE, int nT) {
    int idx = blockIdx.x * blockDim.x + threadIdx.x;
    if (idx >= nT) return;
    int src, dst;
    if (idx < nE) { src = ei[idx]; dst = ei[nE + idx]; } else { src = dst = idx - nE; }
    int pos = atomicAdd(&cursor[dst], 1);
    csr_src[pos] = src;
}

// ============ fused per-dst-node softmax + aggregation + bias + ELU ============
// one 64-lane wave per node, 4 waves/block
template <int H>
__global__ void node_agg(const int* __restrict__ rowptr, const int* __restrict__ csr,
                         const float* __restrict__ as_, const float* __restrict__ ad_,
                         const float* __restrict__ hbuf, const float* __restrict__ b,
                         float* __restrict__ out, int n) {
    int node = blockIdx.x * 4 + (threadIdx.x >> 6);
    int lane = threadIdx.x & 63;
    if (node >= n) return;
    int beg = rowptr[node], end = rowptr[node + 1];

    float adn[H], mh[H], sh[H];
#pragma unroll
    for (int h = 0; h < H; h++) {
        adn[h] = ad_[node * H + h];
        mh[h] = -1e30f;
        sh[h] = 0.f;
    }
    // pass A: online softmax stats, lanes stride over edges
    for (int i = beg + lane; i < end; i += 64) {
        int src = csr[i];
#pragma unroll
        for (int h = 0; h < H; h++) {
            float ev = as_[src * H + h] + adn[h];
            ev = ev > 0.f ? ev : 0.2f * ev;
            if (ev > mh[h]) {
                sh[h] = sh[h] * __expf(mh[h] - ev) + 1.f;
                mh[h] = ev;
            } else {
                sh[h] += __expf(ev - mh[h]);
            }
        }
    }
    // combine (m,s) across the wave
#pragma unroll
    for (int off = 32; off > 0; off >>= 1) {
#pragma unroll
        for (int h = 0; h < H; h++) {
            float m2 = __shfl_down(mh[h], off);
            float s2 = __shfl_down(sh[h], off);
            float mn = fmaxf(mh[h], m2);
            sh[h] = sh[h] * __expf(mh[h] - mn) + s2 * __expf(m2 - mn);
            mh[h] = mn;
        }
    }
#pragma unroll
    for (int h = 0; h < H; h++) {
        mh[h] = __shfl(mh[h], 0);
        sh[h] = __shfl(sh[h], 0);
        sh[h] += 1e-16f;
    }

    // pass B: weighted gather-accumulate, whole wave per edge, lane = channel
    float acc[H];
#pragma unroll
    for (int h = 0; h < H; h++) acc[h] = 0.f;
    for (int base = beg; base < end; base += 64) {
        int cnt = end - base;
        if (cnt > 64) cnt = 64;
        int my = (lane < cnt) ? csr[base + lane] : 0;
        for (int j = 0; j < cnt; j++) {
            int src = __shfl(my, j);
#pragma unroll
            for (int h = 0; h < H; h++) {
                float ev = as_[src * H + h] + adn[h];
                ev = ev > 0.f ? ev : 0.2f * ev;
                float al = __expf(ev - mh[h]) / sh[h];
                acc[h] += al * hbuf[(size_t)src * (H * 64) + h * 64 + lane];
            }
        }
    }
    // epilogue: bias + ELU
#pragma unroll
    for (int h = 0; h < H; h++) {
        float v = acc[h] + b[h * 64 + lane];
        out[(size_t)node * (H * 64) + h * 64 + lane] = v > 0.f ? v : __expf(v) - 1.f;
    }
}

// ============ fused classifier ============
__global__ void classifier_kernel(const float* __restrict__ z, const float* __restrict__ W3,
                                  const float* __restrict__ b3, const float* __restrict__ W4,
                                  const float* __restrict__ b4, float* __restrict__ out, int n) {
    __shared__ float zt[64][65];
    __shared__ float w3s[64 * 32];
    __shared__ float hid[64][33];
    __shared__ float w4s[64], b3s[32], b4s[2];
    int t = threadIdx.x;
    int r0 = blockIdx.x * 64;
#pragma unroll
    for (int i = 0; i < 16; i++) {
        int j = i * 256 + t;
        int row = j >> 6, col = j & 63;
        int gr = r0 + row;
        zt[row][col] = (gr < n) ? z[(size_t)gr * 64 + col] : 0.f;
    }
#pragma unroll
    for (int i = 0; i < 8; i++) w3s[i * 256 + t] = W3[i * 256 + t];
    if (t < 64) w4s[t] = W4[t];
    if (t < 32) b3s[t] = b3[t];
    if (t < 2) b4s[t] = b4[t];
    __syncthreads();
#pragma unroll
    for (int i = 0; i < 8; i++) {
        int row = (t >> 5) + i * 8;
        int col = t & 31;
        float acc = b3s[col];
#pragma unroll
        for (int k = 0; k < 64; k++) acc += zt[row][k] * w3s[k * 32 + col];
        hid[row][col] = acc > 0.f ? acc : 0.f;
    }
    __syncthreads();
    if (t < 128) {
        int row = t >> 1, c = t & 1;
        int gr = r0 + row;
        if (gr < n) {
            float acc = b4s[c];
#pragma unroll
            for (int k = 0; k < 32; k++) acc += hid[row][k] * w4s[k * 2 + c];
            out[(size_t)gr * 2 + c] = acc;
        }
    }
}

extern "C" void kernel_launch(void* const* d_in, const int* in_sizes, int n_in,
                              void* d_out, int out_size, void* d_ws, size_t ws_size,
                              hipStream_t stream) {
    const float* x      = (const float*)d_in[0];
    const int*   ei     = (const int*)d_in[1];
    const float* W1     = (const float*)d_in[2];
    const float* a_src1 = (const float*)d_in[3];
    const float* a_dst1 = (const float*)d_in[4];
    const float* b1     = (const float*)d_in[5];
    const float* W2     = (const float*)d_in[6];
    const float* a_src2 = (const float*)d_in[7];
    const float* a_dst2 = (const float*)d_in[8];
    const float* b2     = (const float*)d_in[9];
    const float* W3     = (const float*)d_in[10];
    const float* b3     = (const float*)d_in[11];
    const float* W4     = (const float*)d_in[12];
    const float* b4     = (const float*)d_in[13];
    float* out = (float*)d_out;

    const int N = NNODES, E = NEDGES, ET = E + N;
    const int NB = (N + 255) / 256;  // 196 scan blocks

    float* ws = (float*)d_ws;
    size_t o = 0;
    float* h1   = ws + o; o += (size_t)N * 256;
    float* out1 = ws + o; o += (size_t)N * 256;
    float* as1  = ws + o; o += (size_t)N * 4;
    float* ad1  = ws + o; o += (size_t)N * 4;
    int* ibase     = (int*)(ws + o);
    int* rowptr    = ibase;             // N+1
    int* cursor    = rowptr + (N + 1);  // N (also used as deg)
    int* blocksums = cursor + N;        // 256
    int* csr_src   = blocksums + 256;   // ET
    // layer-2 buffers reuse h1 region (dead after layer-1 aggregation)
    float* h2   = h1;
    float* out2 = h1 + (size_t)N * 64;

    dim3 blk(256);

    // ---- CSR build (shared by both layers) ----
    hipMemsetAsync(cursor, 0, (size_t)N * sizeof(int), stream);
    deg_hist<<<(ET + 255) / 256, blk, 0, stream>>>(ei, cursor, E, ET);
    scan_block<<<NB, blk, 0, stream>>>(cursor, rowptr, blocksums, N);
    scan_sums<<<1, blk, 0, stream>>>(blocksums, NB);
    scan_add<<<NB, blk, 0, stream>>>(rowptr, blocksums, cursor, N, ET);
    csr_scatter<<<(ET + 255) / 256, blk, 0, stream>>>(ei, cursor, csr_src, E, ET);

    // ---- Layer 1 (H=4, C=64) ----
    gemm_f32<<<dim3(4, (N + 63) / 64), blk, 0, stream>>>(x, W1, h1, N, 128, 256);
    asad_kernel<4><<<(N + 3) / 4, blk, 0, stream>>>(h1, a_src1, a_dst1, as1, ad1, N);
    node_agg<4><<<(N + 3) / 4, blk, 0, stream>>>(rowptr, csr_src, as1, ad1, h1, b1, out1, N);

    // ---- Layer 2 (H=1, C=64) ----
    gemm_f32<<<dim3(1, (N + 63) / 64), blk, 0, stream>>>(out1, W2, h2, N, 256, 64);
    asad_kernel<1><<<(N + 3) / 4, blk, 0, stream>>>(h2, a_src2, a_dst2, as1, ad1, N);
    node_agg<1><<<(N + 3) / 4, blk, 0, stream>>>(rowptr, csr_src, as1, ad1, h2, b2, out2, N);

    // ---- Classifier ----
    classifier_kernel<<<(N + 63) / 64, blk, 0, stream>>>(out2, W3, b3, W4, b4, out, N);
}